// Round 9
// baseline (254.740 us; speedup 1.0000x reference)
//
#include <hip/hip_runtime.h>
#include <hip/hip_fp16.h>

typedef unsigned int uint32;

#define B_ 16
#define N_ 400
#define D_ 256
#define H_ 8
#define DH_ 32
#define NW_ 4

#if __has_builtin(__builtin_amdgcn_exp2f)
#define EXP2(x) __builtin_amdgcn_exp2f(x)
#else
#define EXP2(x) exp2f(x)
#endif

// log2(e)/sqrt(32): exp(|qk/sqrt(32) * w|) == exp2(|qk*SCL * w|)
#define QK_SCL 0.2550348f

using bf16x8 = __attribute__((ext_vector_type(8))) short;
using f16x8  = __attribute__((ext_vector_type(8))) _Float16;
using f16x4  = __attribute__((ext_vector_type(4))) _Float16;
using f32x4  = __attribute__((ext_vector_type(4))) float;

__device__ __forceinline__ ushort f2b(float f) {
  uint32 u = __float_as_uint(f);
  uint32 r = (u + 0x7fffu + ((u >> 16) & 1u)) >> 16;
  return (ushort)r;
}

// ---------------------------------------------------------------------------
// Convert fp32 inputs -> bf16 scratch copies (x + 6 weight matrices)
// ---------------------------------------------------------------------------
__global__ __launch_bounds__(256) void convert_kernel(
    const float* __restrict__ x,  const float* __restrict__ wq,
    const float* __restrict__ wk, const float* __restrict__ wv,
    const float* __restrict__ wo, const float* __restrict__ w1,
    const float* __restrict__ w2,
    ushort* __restrict__ xb,  ushort* __restrict__ wqb,
    ushort* __restrict__ wkb, ushort* __restrict__ wvb,
    ushort* __restrict__ wob, ushort* __restrict__ w1b,
    ushort* __restrict__ w2b) {
  int gid = blockIdx.x * 256 + threadIdx.x;   // unit = 4 floats
  const float* src; ushort* dst;
  if      (gid < 409600) { src = x;  dst = xb;  }
  else if ((gid -= 409600) < 16384) { src = wq; dst = wqb; }
  else if ((gid -= 16384) < 16384)  { src = wk; dst = wkb; }
  else if ((gid -= 16384) < 16384)  { src = wv; dst = wvb; }
  else if ((gid -= 16384) < 16384)  { src = wo; dst = wob; }
  else if ((gid -= 16384) < 65536)  { src = w1; dst = w1b; }
  else { gid -= 65536; src = w2; dst = w2b; }
  float4 f = ((const float4*)src)[gid];
  ushort4 u;
  u.x = f2b(f.x); u.y = f2b(f.y); u.z = f2b(f.z); u.w = f2b(f.w);
  *(ushort4*)&dst[(size_t)gid * 4] = u;
}

// ---------------------------------------------------------------------------
// gemm128: C[M,N] = A[M,K] @ W[N,K]^T + bias, fused epilogue.
// 128x128 tile, BK=32, 256 threads as 2x2 waves; each wave owns a 64x64
// quadrant (acc[4][4] fragments of 16x16). Double-buffered LDS with +8 pad
// (row stride 80 B -> 2 lanes/bank on ds_read_b128, conflict-free).
// 16 MFMA per wave per K-step vs 4 in the old 64x64 kernel -> 4x the MFMA
// density per barrier. Replaces gemm_bt for attn-out / ffn1 / ffn2
// (M=6400 and N in {256,1024} divide 128 exactly).
// ---------------------------------------------------------------------------
template <int RELU, int RESID, int OUT_F32, int OUT_BF16>
__global__ __launch_bounds__(256) void gemm128(
    const ushort* __restrict__ A, const ushort* __restrict__ W,
    const float* __restrict__ bias, const float* __restrict__ resid,
    float* __restrict__ outf, ushort* __restrict__ outb,
    int M, int N, int K) {
  __shared__ __align__(16) ushort As[2][128 * 40];  // +8 bf16 pad per row
  __shared__ __align__(16) ushort Ws[2][128 * 40];
  int t = threadIdx.x;
  int l = t & 63, w = t >> 6;
  int wr = w >> 1, wc = w & 1;  // 2x2 wave grid over the 128x128 tile
  int n0 = blockIdx.x * 128, m0 = blockIdx.y * 128;
  int lrow = l & 15, lk = (l >> 4) * 8;

  // staging: thread t loads rows r0 and r0+64 (quarter-row q) of A and W
  int r0 = t >> 2, q = (t & 3) * 8;
  const uint4* agA = (const uint4*)&A[(size_t)(m0 + r0) * K + q];
  const uint4* agB = (const uint4*)&A[(size_t)(m0 + r0 + 64) * K + q];
  const uint4* wgA = (const uint4*)&W[(size_t)(n0 + r0) * K + q];
  const uint4* wgB = (const uint4*)&W[(size_t)(n0 + r0 + 64) * K + q];
  int nk = K >> 5;
  uint4 a0 = agA[0], a1 = agB[0], b0 = wgA[0], b1 = wgB[0];

  f32x4 acc[4][4];
#pragma unroll
  for (int fr = 0; fr < 4; fr++)
#pragma unroll
    for (int fc = 0; fc < 4; fc++) acc[fr][fc] = {0.f, 0.f, 0.f, 0.f};

  for (int kk = 0; kk < nk; kk++) {
    int cur = kk & 1;
    *(uint4*)&As[cur][r0 * 40 + q]        = a0;
    *(uint4*)&As[cur][(r0 + 64) * 40 + q] = a1;
    *(uint4*)&Ws[cur][r0 * 40 + q]        = b0;
    *(uint4*)&Ws[cur][(r0 + 64) * 40 + q] = b1;
    if (kk + 1 < nk) {
      a0 = agA[(size_t)(kk + 1) * 4]; a1 = agB[(size_t)(kk + 1) * 4];
      b0 = wgA[(size_t)(kk + 1) * 4]; b1 = wgB[(size_t)(kk + 1) * 4];
    }
    __syncthreads();
    bf16x8 af[4], bf[4];
#pragma unroll
    for (int fr = 0; fr < 4; fr++)
      af[fr] = *(const bf16x8*)&As[cur][(wr * 64 + fr * 16 + lrow) * 40 + lk];
#pragma unroll
    for (int fc = 0; fc < 4; fc++)
      bf[fc] = *(const bf16x8*)&Ws[cur][(wc * 64 + fc * 16 + lrow) * 40 + lk];
#pragma unroll
    for (int fr = 0; fr < 4; fr++)
#pragma unroll
      for (int fc = 0; fc < 4; fc++)
        acc[fr][fc] =
            __builtin_amdgcn_mfma_f32_16x16x32_bf16(af[fr], bf[fc], acc[fr][fc], 0, 0, 0);
  }

  // C/D layout: col = lane&15, row = (lane>>4)*4 + reg   [verified m89/m91]
#pragma unroll
  for (int fc = 0; fc < 4; fc++) {
    int n = n0 + wc * 64 + fc * 16 + lrow;
    float bv = bias[n];
#pragma unroll
    for (int fr = 0; fr < 4; fr++) {
#pragma unroll
      for (int r = 0; r < 4; r++) {
        int m = m0 + wr * 64 + fr * 16 + (l >> 4) * 4 + r;
        float v = acc[fr][fc][r] + bv;
        if (RELU)  v = fmaxf(v, 0.f);
        if (RESID) v += resid[(size_t)m * N + n];
        if (OUT_F32)  outf[(size_t)m * N + n] = v;
        if (OUT_BF16) outb[(size_t)m * N + n] = f2b(v);
      }
    }
  }
}

// ---------------------------------------------------------------------------
// Fused QKV GEMM: one launch, z picks {q,k,v}. 64x64 MFMA core (unchanged).
// q -> fp16 HEAD-MAJOR [b][h][m][32], pre-scaled by QK_SCL.
// k -> fp16 HEAD-MAJOR [b][h][m][32].
// v -> fp16 TRANSPOSED vt[b][d][m] (stride N_=400); d = h*32+dh.
// ---------------------------------------------------------------------------
__global__ __launch_bounds__(256) void qkv_gemm(
    const ushort* __restrict__ xb, const ushort* __restrict__ wq,
    const ushort* __restrict__ wk, const ushort* __restrict__ wv,
    const float* __restrict__ bq, const float* __restrict__ bk,
    const float* __restrict__ bv,
    _Float16* __restrict__ qh, _Float16* __restrict__ kh,
    _Float16* __restrict__ vt) {
  __shared__ __align__(16) ushort As[2][64 * 40];
  __shared__ __align__(16) ushort Ws[2][64 * 40];
  int z = blockIdx.z;
  const ushort* W = (z == 0) ? wq : (z == 1) ? wk : wv;
  const float* bias = (z == 0) ? bq : (z == 1) ? bk : bv;

  int t = threadIdx.x;
  int l = t & 63, w = t >> 6;
  int n0 = blockIdx.x * 64, m0 = blockIdx.y * 64;
  int srow = t >> 2, sc = (t & 3) * 8;
  int lrow = l & 15, lk = (l >> 4) * 8;

  const uint4* ag = (const uint4*)&xb[(size_t)(m0 + srow) * 256 + sc];
  const uint4* wg = (const uint4*)&W[(size_t)(n0 + srow) * 256 + sc];
  uint4 ar = ag[0], wr = wg[0];

  f32x4 acc[4];
#pragma unroll
  for (int nt = 0; nt < 4; nt++) acc[nt] = {0.f, 0.f, 0.f, 0.f};

  for (int kk = 0; kk < 8; kk++) {
    int cur = kk & 1;
    *(uint4*)&As[cur][srow * 40 + sc] = ar;
    *(uint4*)&Ws[cur][srow * 40 + sc] = wr;
    if (kk + 1 < 8) { ar = ag[(kk + 1) * 4]; wr = wg[(kk + 1) * 4]; }
    __syncthreads();
    bf16x8 af = *(const bf16x8*)&As[cur][(16 * w + lrow) * 40 + lk];
#pragma unroll
    for (int nt = 0; nt < 4; nt++) {
      bf16x8 bf = *(const bf16x8*)&Ws[cur][(nt * 16 + lrow) * 40 + lk];
      acc[nt] = __builtin_amdgcn_mfma_f32_16x16x32_bf16(af, bf, acc[nt], 0, 0, 0);
    }
  }

  int mb = m0 + 16 * w + (l >> 4) * 4;  // multiple of 4 -> never crosses b*400
  int bb = mb / 400;
  int mi = mb - bb * 400;
#pragma unroll
  for (int nt = 0; nt < 4; nt++) {
    int n = n0 + nt * 16 + lrow;
    float bvv = bias[n];
    if (z < 2) {
      _Float16* out = z ? kh : qh;
      float scl = z ? 1.f : QK_SCL;
      int hh = n >> 5, dd = n & 31;
      _Float16* dst = out + (((size_t)(bb * 8 + hh)) * 400 + mi) * 32 + dd;
#pragma unroll
      for (int r = 0; r < 4; r++)
        dst[(size_t)r * 32] = (_Float16)((acc[nt][r] + bvv) * scl);
    } else {
      _Float16 h4[4];
#pragma unroll
      for (int r = 0; r < 4; r++) h4[r] = (_Float16)(acc[nt][r] + bvv);
      *(uint2*)&vt[((size_t)bb * 256 + n) * 400 + mi] = *(uint2*)h4;
    }
  }
}

// ---------------------------------------------------------------------------
// Fused attention v9 (FROZEN from round 8, best measured: 63.4 us).
// v8 clustered loads + one-group-ahead double-buffered aw prefetch.
//   P1: S[16n][400m] = (Q*scl) @ K^T via 25 mfma_16x16x32_f16 -> LDS fp16
//   P2: one wave per row, 4 row-groups, prefetched double-buffered aw;
//       e in f16 regs; 4 interleaved 6-step shfl_xor chains; packed pass 2.
//   P3b: O = S @ V, 13 chunks over 4 waves; cross-wave LDS reduce (8 KB).
// ---------------------------------------------------------------------------
#define SP 416  // S row pitch in halves (832 B, 16B-aligned); 13 chunks of 32

__global__ __launch_bounds__(256, 4) void attn_kernel(
    const _Float16* __restrict__ qh, const _Float16* __restrict__ kh,
    const _Float16* __restrict__ vt, const float* __restrict__ aw,
    float* __restrict__ scores, ushort* __restrict__ attnb) {
  __shared__ __align__(16) char smem[16 * SP * 2];  // 13312 B (Of needs 8192)
  __half* S = (__half*)smem;               // [16][SP] fp16

  int id = blockIdx.x;
  int c = ((id >> 6) << 3) | (id & 7);  // 0..399: (b, n-tile) combo
  int hh = (id >> 3) & 7;
  int b = c / 25;
  int n0 = (c - b * 25) * 16;

  int t = threadIdx.x;
  int w = t >> 6, l = t & 63;
  int lq = l >> 4, lr = l & 15;

  // ---- P1: S = (Q*scl) @ K^T (25 m-tiles over 4 waves) ----
  {
    const _Float16* qbase = qh + (((size_t)(b * 8 + hh)) * 400 + n0) * 32;
    const _Float16* kbase = kh + ((size_t)(b * 8 + hh)) * 400 * 32;
    f16x8 af = *(const f16x8*)(qbase + lr * 32 + lq * 8);
    for (int mt = w; mt < 25; mt += 4) {
      f16x8 bf = *(const f16x8*)(kbase + (size_t)(mt * 16 + lr) * 32 + lq * 8);
      f32x4 cc = {0.f, 0.f, 0.f, 0.f};
      cc = __builtin_amdgcn_mfma_f32_16x16x32_f16(af, bf, cc, 0, 0, 0);
#pragma unroll
      for (int r = 0; r < 4; r++)
        S[(lq * 4 + r) * SP + mt * 16 + lr] = __float2half(cc[r]);
    }
  }
  __syncthreads();

  // ---- P2: single aw sweep; double-buffered 1-group-ahead prefetch ----
  {
    int m0 = l * 4, m1 = 256 + l * 4;
    bool act = (l < 36);       // chunk1 covers m in [256,400) with 36 lanes
    int m1c = act ? m1 : m0;   // clamped: all lanes load a valid address
    const float* awb = aw + (((size_t)(b * 4)) * 400 + n0) * 400;
    float* scb = scores + (((size_t)(b * 8 + hh)) * 400 + n0) * 400;

    float4 A0[4], A1[4], B0[4], B1[4];
    {
      const float* awn = awb + (size_t)w * 400;  // group 0 row
#pragma unroll
      for (int i = 0; i < 4; i++) {
        A0[i] = *(const float4*)(awn + (size_t)i * 160000 + m0);
        A1[i] = *(const float4*)(awn + (size_t)i * 160000 + m1c);
      }
    }

    auto grp = [&](int n, float4 (&c0)[4], float4 (&c1)[4],
                   float4 (&p0)[4], float4 (&p1)[4], bool pf) {
      if (pf) {
        const float* awn = awb + (size_t)(n + 4) * 400;
#pragma unroll
        for (int i = 0; i < 4; i++) {
          p0[i] = *(const float4*)(awn + (size_t)i * 160000 + m0);
          p1[i] = *(const float4*)(awn + (size_t)i * 160000 + m1c);
        }
      }
      _Float16* srow = (_Float16*)S + (size_t)n * SP;
      float* scout = scb + (size_t)n * 400;

      f16x4 s0 = *(const f16x4*)(srow + m0);
      float q0[4], q1[4];
#pragma unroll
      for (int j = 0; j < 4; j++) q0[j] = (float)s0[j];
      if (act) {
        f16x4 s1 = *(const f16x4*)(srow + m1);
#pragma unroll
        for (int j = 0; j < 4; j++) q1[j] = (float)s1[j];
      } else {
#pragma unroll
        for (int j = 0; j < 4; j++) q1[j] = 0.f;
      }

      f16x4 e0[4], e1[4];
      float z[4];
#pragma unroll
      for (int i = 0; i < 4; i++) {
        float zz0 = 0.f, zz1 = 0.f;
#pragma unroll
        for (int j = 0; j < 4; j++) {
          float tt = q0[j] * ((const float*)&c0[i])[j];
          float ef = EXP2(fabsf(tt));
          zz0 += ef;
          e0[i][j] = (_Float16)copysignf(ef, tt);
        }
#pragma unroll
        for (int j = 0; j < 4; j++) {
          float tt = q1[j] * ((const float*)&c1[i])[j];
          float ef = EXP2(fabsf(tt));
          zz1 += ef;
          e1[i][j] = (_Float16)copysignf(ef, tt);
        }
        z[i] = zz0 + (act ? zz1 : 0.f);  // cndmask, no divergence
      }

#pragma unroll
      for (int o = 1; o <= 32; o <<= 1) {
#pragma unroll
        for (int i = 0; i < 4; i++) z[i] += __shfl_xor(z[i], o);
      }

      f16x4 o0, o1;
#pragma unroll
      for (int j = 0; j < 4; j++) { o0[j] = (_Float16)0.f; o1[j] = (_Float16)0.f; }
#pragma unroll
      for (int i = 0; i < 4; i++) {
        _Float16 zh = (_Float16)(0.25f / (z[i] + 1e-10f));  // folds the /NW
        f16x4 zv = {zh, zh, zh, zh};
        o0 += e0[i] * zv;
        o1 += e1[i] * zv;
      }

      float4 so;
#pragma unroll
      for (int j = 0; j < 4; j++) ((float*)&so)[j] = (float)o0[j];
      *(float4*)(scout + m0) = so;
      *(f16x4*)(srow + m0) = o0;
      if (act) {
        float4 s1o;
#pragma unroll
        for (int j = 0; j < 4; j++) ((float*)&s1o)[j] = (float)o1[j];
        *(float4*)(scout + m1) = s1o;
        *(f16x4*)(srow + m1) = o1;
      } else if (l < 40) {
        f16x4 hz;
#pragma unroll
        for (int j = 0; j < 4; j++) hz[j] = (_Float16)0.f;
        *(f16x4*)(srow + m1) = hz;  // zero-pad cols 400..415 for PV chunks
      }
    };

    grp(w,      A0, A1, B0, B1, true);
    grp(4 + w,  B0, B1, A0, A1, true);
    grp(8 + w,  A0, A1, B0, B1, true);
    grp(12 + w, B0, B1, A0, A1, false);
  }
  __syncthreads();

  // ---- P3b: O = S @ V (13 chunks of 32 m, split across 4 waves) ----
  const _Float16* vbase = vt + (((size_t)b) * 256 + hh * 32) * 400;
  f32x4 a0 = {0.f, 0.f, 0.f, 0.f}, a1 = {0.f, 0.f, 0.f, 0.f};
  const _Float16* Sh = (const _Float16*)S;
  for (int c2 = w; c2 < 13; c2 += 4) {
    f16x8 sf = *(const f16x8*)(Sh + lr * SP + c2 * 32 + lq * 8);
    f16x8 v0 = *(const f16x8*)(vbase + (size_t)lr * 400 + c2 * 32 + lq * 8);
    f16x8 v1 = *(const f16x8*)(vbase + (size_t)(16 + lr) * 400 + c2 * 32 + lq * 8);
    a0 = __builtin_amdgcn_mfma_f32_16x16x32_f16(sf, v0, a0, 0, 0, 0);
    a1 = __builtin_amdgcn_mfma_f32_16x16x32_f16(sf, v1, a1, 0, 0, 0);
  }
  __syncthreads();  // all S reads done before overwriting as float scratch
  float* Of = (float*)smem;  // [4w][16n][32d] = 8 KB
#pragma unroll
  for (int r = 0; r < 4; r++) {
    Of[(w * 16 + lq * 4 + r) * 32 + lr] = a0[r];
    Of[(w * 16 + lq * 4 + r) * 32 + 16 + lr] = a1[r];
  }
  __syncthreads();
  for (int o = t; o < 512; o += 256) {
    int n = o >> 5, d = o & 31;
    float s = Of[n * 32 + d] + Of[512 + n * 32 + d] +
              Of[1024 + n * 32 + d] + Of[1536 + n * 32 + d];
    attnb[((size_t)(b * 400 + n0 + n)) * 256 + hh * 32 + d] = f2b(s);
  }
}

// ---------------------------------------------------------------------------
// LayerNorm over last dim (256). One block per row.
// ---------------------------------------------------------------------------
__global__ __launch_bounds__(256) void ln_kernel(
    const float* __restrict__ src, const float* __restrict__ g,
    const float* __restrict__ be, float* __restrict__ outf,
    ushort* __restrict__ outb) {
  int row = blockIdx.x, t = threadIdx.x;
  float v = src[(size_t)row * 256 + t];
  __shared__ float red[4];
  float s = v;
#pragma unroll
  for (int o = 32; o > 0; o >>= 1) s += __shfl_down(s, o, 64);
  if ((t & 63) == 0) red[t >> 6] = s;
  __syncthreads();
  float mean = (red[0] + red[1] + red[2] + red[3]) * (1.f / 256.f);
  __syncthreads();
  float d = v - mean;
  s = d * d;
#pragma unroll
  for (int o = 32; o > 0; o >>= 1) s += __shfl_down(s, o, 64);
  if ((t & 63) == 0) red[t >> 6] = s;
  __syncthreads();
  float var = (red[0] + red[1] + red[2] + red[3]) * (1.f / 256.f);
  float y = d * rsqrtf(var + 1e-5f) * g[t] + be[t];
  outf[(size_t)row * 256 + t] = y;
  if (outb) outb[(size_t)row * 256 + t] = f2b(y);
}

// ---------------------------------------------------------------------------
extern "C" void kernel_launch(void* const* d_in, const int* in_sizes, int n_in,
                              void* d_out, int out_size, void* d_ws,
                              size_t ws_size, hipStream_t stream) {
  const float* x   = (const float*)d_in[0];
  const float* aw  = (const float*)d_in[1];
  const float* Wq  = (const float*)d_in[2];
  const float* bq  = (const float*)d_in[3];
  const float* Wk  = (const float*)d_in[4];
  const float* bk  = (const float*)d_in[5];
  const float* Wv  = (const float*)d_in[6];
  const float* bv  = (const float*)d_in[7];
  const float* Wo  = (const float*)d_in[8];
  const float* bo  = (const float*)d_in[9];
  const float* g1  = (const float*)d_in[10];
  const float* be1 = (const float*)d_in[11];
  const float* W1  = (const float*)d_in[12];
  const float* b1  = (const float*)d_in[13];
  const float* W2  = (const float*)d_in[14];
  const float* b2  = (const float*)d_in[15];
  const float* g2  = (const float*)d_in[16];
  const float* be2 = (const float*)d_in[17];

  if (ws_size < 34340864) return;  // scratch layout requirement

  char* ws = (char*)d_ws;
  ushort*   xb    = (ushort*)(ws + 0);          // 3,276,800
  ushort*   wqb   = (ushort*)(ws + 3276800);    //   131,072
  ushort*   wkb   = (ushort*)(ws + 3407872);
  ushort*   wvb   = (ushort*)(ws + 3538944);
  ushort*   wob   = (ushort*)(ws + 3670016);
  ushort*   w1b   = (ushort*)(ws + 3801088);    //   524,288
  ushort*   w2b   = (ushort*)(ws + 4325376);    //   524,288
  _Float16* qhb   = (_Float16*)(ws + 4849664);  // 3,276,800  [b][h][m][32]*scl
  _Float16* khb   = (_Float16*)(ws + 8126464);  //            [b][h][m][32]
  _Float16* vtb   = (_Float16*)(ws + 11403264); //            [b][d][m]
  ushort*   attnb = (ushort*)(ws + 14680064);
  float*    ao    = (float*)(ws + 17956864);    // 6,553,600 (reused as ffn2)
  float*    hbuf  = (float*)(ws + 24510464);    // 6,553,600
  ushort*   hb    = (ushort*)(ws + 31064064);   // 3,276,800 -> total 34,340,864
  ushort*   ffn1b = (ushort*)qhb;  // reuse q/k/v region, dead by then
  float*    ffn2  = ao;            // reuse ao, dead after LN1

  float* yout   = (float*)d_out;
  float* scores = yout + 1638400;

  convert_kernel<<<2368, 256, 0, stream>>>(x, Wq, Wk, Wv, Wo, W1, W2,
                                           xb, wqb, wkb, wvb, wob, w1b, w2b);
  qkv_gemm<<<dim3(4, 100, 3), 256, 0, stream>>>(
      xb, wqb, wkb, wvb, bq, bk, bv, qhb, khb, vtb);
  attn_kernel<<<3200, 256, 0, stream>>>(qhb, khb, vtb, aw, scores, attnb);
  gemm128<0, 1, 1, 0><<<dim3(2, 50), 256, 0, stream>>>(
      attnb, wob, bo, x, ao, nullptr, 6400, 256, 256);
  ln_kernel<<<6400, 256, 0, stream>>>(ao, g1, be1, hbuf, hb);
  gemm128<1, 0, 0, 1><<<dim3(8, 50), 256, 0, stream>>>(
      hb, w1b, b1, nullptr, nullptr, ffn1b, 6400, 1024, 256);
  gemm128<0, 1, 1, 0><<<dim3(2, 50), 256, 0, stream>>>(
      ffn1b, w2b, b2, hbuf, ffn2, nullptr, 6400, 256, 1024);
  ln_kernel<<<6400, 256, 0, stream>>>(ffn2, g2, be2, yout, nullptr);
}

// Round 10
// 241.850 us; speedup vs baseline: 1.0533x; 1.0533x over previous
//
#include <hip/hip_runtime.h>
#include <hip/hip_fp16.h>

typedef unsigned int uint32;

#define B_ 16
#define N_ 400
#define D_ 256
#define H_ 8
#define DH_ 32
#define NW_ 4

#if __has_builtin(__builtin_amdgcn_exp2f)
#define EXP2(x) __builtin_amdgcn_exp2f(x)
#else
#define EXP2(x) exp2f(x)
#endif

// log2(e)/sqrt(32): exp(|qk/sqrt(32) * w|) == exp2(|qk*SCL * w|)
#define QK_SCL 0.2550348f

using bf16x8 = __attribute__((ext_vector_type(8))) short;
using f16x8  = __attribute__((ext_vector_type(8))) _Float16;
using f16x4  = __attribute__((ext_vector_type(4))) _Float16;
using f32x4  = __attribute__((ext_vector_type(4))) float;

__device__ __forceinline__ ushort f2b(float f) {
  uint32 u = __float_as_uint(f);
  uint32 r = (u + 0x7fffu + ((u >> 16) & 1u)) >> 16;
  return (ushort)r;
}

// ---------------------------------------------------------------------------
// Convert fp32 inputs -> bf16 scratch copies (x + 6 weight matrices)
// ---------------------------------------------------------------------------
__global__ __launch_bounds__(256) void convert_kernel(
    const float* __restrict__ x,  const float* __restrict__ wq,
    const float* __restrict__ wk, const float* __restrict__ wv,
    const float* __restrict__ wo, const float* __restrict__ w1,
    const float* __restrict__ w2,
    ushort* __restrict__ xb,  ushort* __restrict__ wqb,
    ushort* __restrict__ wkb, ushort* __restrict__ wvb,
    ushort* __restrict__ wob, ushort* __restrict__ w1b,
    ushort* __restrict__ w2b) {
  int gid = blockIdx.x * 256 + threadIdx.x;   // unit = 4 floats
  const float* src; ushort* dst;
  if      (gid < 409600) { src = x;  dst = xb;  }
  else if ((gid -= 409600) < 16384) { src = wq; dst = wqb; }
  else if ((gid -= 16384) < 16384)  { src = wk; dst = wkb; }
  else if ((gid -= 16384) < 16384)  { src = wv; dst = wvb; }
  else if ((gid -= 16384) < 16384)  { src = wo; dst = wob; }
  else if ((gid -= 16384) < 65536)  { src = w1; dst = w1b; }
  else { gid -= 65536; src = w2; dst = w2b; }
  float4 f = ((const float4*)src)[gid];
  ushort4 u;
  u.x = f2b(f.x); u.y = f2b(f.y); u.z = f2b(f.z); u.w = f2b(f.w);
  *(ushort4*)&dst[(size_t)gid * 4] = u;
}

// ---------------------------------------------------------------------------
// Generic bf16 MFMA GEMM: C[M,N] = A[M,K] @ W[N,K]^T + bias, fused epilogue.
// 64x64 tile, 256 threads (4 waves), double-buffered LDS: 1 barrier / K-step.
// Used for ffn1 (N=1024): grid (16,100)=1600 blocks, parallelism-maximal.
// ---------------------------------------------------------------------------
template <int RELU, int RESID, int OUT_F32, int OUT_BF16>
__global__ __launch_bounds__(256) void gemm_bt(
    const ushort* __restrict__ A, const ushort* __restrict__ W,
    const float* __restrict__ bias, const float* __restrict__ resid,
    float* __restrict__ outf, ushort* __restrict__ outb,
    int M, int N, int K) {
  __shared__ __align__(16) ushort As[2][64 * 40];  // +8 bf16 pad per row
  __shared__ __align__(16) ushort Ws[2][64 * 40];
  int t = threadIdx.x;
  int l = t & 63, w = t >> 6;
  int n0 = blockIdx.x * 64, m0 = blockIdx.y * 64;
  int srow = t >> 2, sc = (t & 3) * 8;
  int lrow = l & 15, lk = (l >> 4) * 8;

  const uint4* ag = (const uint4*)&A[(size_t)(m0 + srow) * K + sc];
  const uint4* wg = (const uint4*)&W[(size_t)(n0 + srow) * K + sc];
  uint4 ar = ag[0], wr = wg[0];
  int nk = K >> 5;

  f32x4 acc[4];
#pragma unroll
  for (int nt = 0; nt < 4; nt++) acc[nt] = {0.f, 0.f, 0.f, 0.f};

  for (int kk = 0; kk < nk; kk++) {
    int cur = kk & 1;
    *(uint4*)&As[cur][srow * 40 + sc] = ar;
    *(uint4*)&Ws[cur][srow * 40 + sc] = wr;
    if (kk + 1 < nk) { ar = ag[(size_t)(kk + 1) * 4]; wr = wg[(size_t)(kk + 1) * 4]; }
    __syncthreads();
    bf16x8 af = *(const bf16x8*)&As[cur][(16 * w + lrow) * 40 + lk];
#pragma unroll
    for (int nt = 0; nt < 4; nt++) {
      bf16x8 bf = *(const bf16x8*)&Ws[cur][(nt * 16 + lrow) * 40 + lk];
      acc[nt] = __builtin_amdgcn_mfma_f32_16x16x32_bf16(af, bf, acc[nt], 0, 0, 0);
    }
  }

  // C/D layout: col = lane&15, row = (lane>>4)*4 + reg   [verified m89/m91]
#pragma unroll
  for (int nt = 0; nt < 4; nt++) {
    int n = n0 + nt * 16 + lrow;
    float bv = bias[n];
#pragma unroll
    for (int r = 0; r < 4; r++) {
      int m = m0 + 16 * w + (l >> 4) * 4 + r;
      float v = acc[nt][r] + bv;
      if (RELU)  v = fmaxf(v, 0.f);
      if (RESID) v += resid[(size_t)m * N + n];
      if (OUT_F32)  outf[(size_t)m * N + n] = v;
      if (OUT_BF16) outb[(size_t)m * N + n] = f2b(v);
    }
  }
}

// ---------------------------------------------------------------------------
// gemm_ln: C = A[M,K] @ W[256,K]^T + bias + resid, then LayerNorm over the
// 256 cols — all in one kernel. Block = 32 rows x FULL 256 cols, so each
// block owns complete rows and LN is an epilogue:
//   per-row sum/sumsq: reduce over fc frags + 4-step shfl_xor over the
//   16 col-lanes -> 4-wave partials in LDS -> mean/var -> normalize in regs.
// Grid 200 (M=6400/32). Replaces {gemm_bt + ln_kernel} pairs: removes one
// launch and ~13 MB round-trip traffic per site.
// OUT_BF16: also write bf16 copy (h for ffn1 input). outf always written.
// ---------------------------------------------------------------------------
template <int OUT_BF16>
__global__ __launch_bounds__(256) void gemm_ln(
    const ushort* __restrict__ A, const ushort* __restrict__ W,
    const float* __restrict__ bias, const float* __restrict__ resid,
    const float* __restrict__ g, const float* __restrict__ be,
    float* __restrict__ outf, ushort* __restrict__ outb, int K) {
  __shared__ __align__(16) ushort As[2][32 * 40];   //  5,120 B
  __shared__ __align__(16) ushort Ws[2][256 * 40];  // 40,960 B
  __shared__ float2 red[4][32];                     //  1,024 B
  int t = threadIdx.x;
  int l = t & 63, w = t >> 6;
  int m0 = blockIdx.x * 32;
  int lrow = l & 15, lk = (l >> 4) * 8;
  int srow = t >> 2, sc = (t & 3) * 8;  // 4 threads per row, 64B segments
  int nk = K >> 5;

  const uint4* ag  = (const uint4*)&A[(size_t)(m0 + srow) * K + sc];  // t<128
  const uint4* wg0 = (const uint4*)&W[(size_t)(srow) * K + sc];
  const uint4* wg1 = (const uint4*)&W[(size_t)(64 + srow) * K + sc];
  const uint4* wg2 = (const uint4*)&W[(size_t)(128 + srow) * K + sc];
  const uint4* wg3 = (const uint4*)&W[(size_t)(192 + srow) * K + sc];

  uint4 ar = {0, 0, 0, 0};
  if (t < 128) ar = ag[0];
  uint4 w0 = wg0[0], w1 = wg1[0], w2 = wg2[0], w3 = wg3[0];

  f32x4 acc[2][4];  // [row-frag][col-frag]
#pragma unroll
  for (int fr = 0; fr < 2; fr++)
#pragma unroll
    for (int fc = 0; fc < 4; fc++) acc[fr][fc] = {0.f, 0.f, 0.f, 0.f};

  for (int kk = 0; kk < nk; kk++) {
    int cur = kk & 1;
    if (t < 128) *(uint4*)&As[cur][srow * 40 + sc] = ar;
    *(uint4*)&Ws[cur][srow * 40 + sc]         = w0;
    *(uint4*)&Ws[cur][(64 + srow) * 40 + sc]  = w1;
    *(uint4*)&Ws[cur][(128 + srow) * 40 + sc] = w2;
    *(uint4*)&Ws[cur][(192 + srow) * 40 + sc] = w3;
    if (kk + 1 < nk) {
      size_t off = (size_t)(kk + 1) * 4;
      if (t < 128) ar = ag[off];
      w0 = wg0[off]; w1 = wg1[off]; w2 = wg2[off]; w3 = wg3[off];
    }
    __syncthreads();
    bf16x8 af[2], bf[4];
#pragma unroll
    for (int fr = 0; fr < 2; fr++)
      af[fr] = *(const bf16x8*)&As[cur][(fr * 16 + lrow) * 40 + lk];
#pragma unroll
    for (int fc = 0; fc < 4; fc++)
      bf[fc] = *(const bf16x8*)&Ws[cur][(w * 64 + fc * 16 + lrow) * 40 + lk];
#pragma unroll
    for (int fr = 0; fr < 2; fr++)
#pragma unroll
      for (int fc = 0; fc < 4; fc++)
        acc[fr][fc] = __builtin_amdgcn_mfma_f32_16x16x32_bf16(
            af[fr], bf[fc], acc[fr][fc], 0, 0, 0);
  }

  // ---- epilogue: v = acc + bias + resid (in place), per-row sum/sumsq ----
  float s[2][4], ss[2][4];
#pragma unroll
  for (int fr = 0; fr < 2; fr++)
#pragma unroll
    for (int r = 0; r < 4; r++) { s[fr][r] = 0.f; ss[fr][r] = 0.f; }

#pragma unroll
  for (int fr = 0; fr < 2; fr++) {
#pragma unroll
    for (int fc = 0; fc < 4; fc++) {
      int n = w * 64 + fc * 16 + lrow;
      float bv = bias[n];
#pragma unroll
      for (int r = 0; r < 4; r++) {
        int m = m0 + fr * 16 + (l >> 4) * 4 + r;
        float v = acc[fr][fc][r] + bv + resid[(size_t)m * 256 + n];
        acc[fr][fc][r] = v;
        s[fr][r] += v;
        ss[fr][r] += v * v;
      }
    }
  }
  // reduce over the 16 col-lanes (xor 1,2,4,8 stays within l&15 group)
#pragma unroll
  for (int o = 1; o <= 8; o <<= 1) {
#pragma unroll
    for (int fr = 0; fr < 2; fr++)
#pragma unroll
      for (int r = 0; r < 4; r++) {
        s[fr][r] += __shfl_xor(s[fr][r], o);
        ss[fr][r] += __shfl_xor(ss[fr][r], o);
      }
  }
  // cross-wave partials
  if (lrow == 0) {
#pragma unroll
    for (int fr = 0; fr < 2; fr++)
#pragma unroll
      for (int r = 0; r < 4; r++) {
        int row = fr * 16 + (l >> 4) * 4 + r;
        red[w][row] = {s[fr][r], ss[fr][r]};
      }
  }
  __syncthreads();

#pragma unroll
  for (int fr = 0; fr < 2; fr++) {
#pragma unroll
    for (int r = 0; r < 4; r++) {
      int row = fr * 16 + (l >> 4) * 4 + r;
      float2 p0 = red[0][row], p1 = red[1][row];
      float2 p2 = red[2][row], p3 = red[3][row];
      float sum = p0.x + p1.x + p2.x + p3.x;
      float sq  = p0.y + p1.y + p2.y + p3.y;
      float mean = sum * (1.f / 256.f);
      float var = sq * (1.f / 256.f) - mean * mean;
      float rinv = rsqrtf(var + 1e-5f);
      int m = m0 + row;
#pragma unroll
      for (int fc = 0; fc < 4; fc++) {
        int n = w * 64 + fc * 16 + lrow;
        float y = (acc[fr][fc][r] - mean) * rinv * g[n] + be[n];
        outf[(size_t)m * 256 + n] = y;
        if (OUT_BF16) outb[(size_t)m * 256 + n] = f2b(y);
      }
    }
  }
}

// ---------------------------------------------------------------------------
// Fused QKV GEMM: one launch, z picks {q,k,v}. 64x64 MFMA core (unchanged).
// q -> fp16 HEAD-MAJOR [b][h][m][32], pre-scaled by QK_SCL.
// k -> fp16 HEAD-MAJOR [b][h][m][32].
// v -> fp16 TRANSPOSED vt[b][d][m] (stride N_=400); d = h*32+dh.
// ---------------------------------------------------------------------------
__global__ __launch_bounds__(256) void qkv_gemm(
    const ushort* __restrict__ xb, const ushort* __restrict__ wq,
    const ushort* __restrict__ wk, const ushort* __restrict__ wv,
    const float* __restrict__ bq, const float* __restrict__ bk,
    const float* __restrict__ bv,
    _Float16* __restrict__ qh, _Float16* __restrict__ kh,
    _Float16* __restrict__ vt) {
  __shared__ __align__(16) ushort As[2][64 * 40];
  __shared__ __align__(16) ushort Ws[2][64 * 40];
  int z = blockIdx.z;
  const ushort* W = (z == 0) ? wq : (z == 1) ? wk : wv;
  const float* bias = (z == 0) ? bq : (z == 1) ? bk : bv;

  int t = threadIdx.x;
  int l = t & 63, w = t >> 6;
  int n0 = blockIdx.x * 64, m0 = blockIdx.y * 64;
  int srow = t >> 2, sc = (t & 3) * 8;
  int lrow = l & 15, lk = (l >> 4) * 8;

  const uint4* ag = (const uint4*)&xb[(size_t)(m0 + srow) * 256 + sc];
  const uint4* wg = (const uint4*)&W[(size_t)(n0 + srow) * 256 + sc];
  uint4 ar = ag[0], wr = wg[0];

  f32x4 acc[4];
#pragma unroll
  for (int nt = 0; nt < 4; nt++) acc[nt] = {0.f, 0.f, 0.f, 0.f};

  for (int kk = 0; kk < 8; kk++) {
    int cur = kk & 1;
    *(uint4*)&As[cur][srow * 40 + sc] = ar;
    *(uint4*)&Ws[cur][srow * 40 + sc] = wr;
    if (kk + 1 < 8) { ar = ag[(kk + 1) * 4]; wr = wg[(kk + 1) * 4]; }
    __syncthreads();
    bf16x8 af = *(const bf16x8*)&As[cur][(16 * w + lrow) * 40 + lk];
#pragma unroll
    for (int nt = 0; nt < 4; nt++) {
      bf16x8 bf = *(const bf16x8*)&Ws[cur][(nt * 16 + lrow) * 40 + lk];
      acc[nt] = __builtin_amdgcn_mfma_f32_16x16x32_bf16(af, bf, acc[nt], 0, 0, 0);
    }
  }

  int mb = m0 + 16 * w + (l >> 4) * 4;  // multiple of 4 -> never crosses b*400
  int bb = mb / 400;
  int mi = mb - bb * 400;
#pragma unroll
  for (int nt = 0; nt < 4; nt++) {
    int n = n0 + nt * 16 + lrow;
    float bvv = bias[n];
    if (z < 2) {
      _Float16* out = z ? kh : qh;
      float scl = z ? 1.f : QK_SCL;
      int hh = n >> 5, dd = n & 31;
      _Float16* dst = out + (((size_t)(bb * 8 + hh)) * 400 + mi) * 32 + dd;
#pragma unroll
      for (int r = 0; r < 4; r++)
        dst[(size_t)r * 32] = (_Float16)((acc[nt][r] + bvv) * scl);
    } else {
      _Float16 h4[4];
#pragma unroll
      for (int r = 0; r < 4; r++) h4[r] = (_Float16)(acc[nt][r] + bvv);
      *(uint2*)&vt[((size_t)bb * 256 + n) * 400 + mi] = *(uint2*)h4;
    }
  }
}

// ---------------------------------------------------------------------------
// Fused attention v9 (FROZEN from round 8, best measured: 63.4 us).
// v8 clustered loads + one-group-ahead double-buffered aw prefetch.
//   P1: S[16n][400m] = (Q*scl) @ K^T via 25 mfma_16x16x32_f16 -> LDS fp16
//   P2: one wave per row, 4 row-groups, prefetched double-buffered aw;
//       e in f16 regs; 4 interleaved 6-step shfl_xor chains; packed pass 2.
//   P3b: O = S @ V, 13 chunks over 4 waves; cross-wave LDS reduce (8 KB).
// ---------------------------------------------------------------------------
#define SP 416  // S row pitch in halves (832 B, 16B-aligned); 13 chunks of 32

__global__ __launch_bounds__(256, 4) void attn_kernel(
    const _Float16* __restrict__ qh, const _Float16* __restrict__ kh,
    const _Float16* __restrict__ vt, const float* __restrict__ aw,
    float* __restrict__ scores, ushort* __restrict__ attnb) {
  __shared__ __align__(16) char smem[16 * SP * 2];  // 13312 B (Of needs 8192)
  __half* S = (__half*)smem;               // [16][SP] fp16

  int id = blockIdx.x;
  int c = ((id >> 6) << 3) | (id & 7);  // 0..399: (b, n-tile) combo
  int hh = (id >> 3) & 7;
  int b = c / 25;
  int n0 = (c - b * 25) * 16;

  int t = threadIdx.x;
  int w = t >> 6, l = t & 63;
  int lq = l >> 4, lr = l & 15;

  // ---- P1: S = (Q*scl) @ K^T (25 m-tiles over 4 waves) ----
  {
    const _Float16* qbase = qh + (((size_t)(b * 8 + hh)) * 400 + n0) * 32;
    const _Float16* kbase = kh + ((size_t)(b * 8 + hh)) * 400 * 32;
    f16x8 af = *(const f16x8*)(qbase + lr * 32 + lq * 8);
    for (int mt = w; mt < 25; mt += 4) {
      f16x8 bf = *(const f16x8*)(kbase + (size_t)(mt * 16 + lr) * 32 + lq * 8);
      f32x4 cc = {0.f, 0.f, 0.f, 0.f};
      cc = __builtin_amdgcn_mfma_f32_16x16x32_f16(af, bf, cc, 0, 0, 0);
#pragma unroll
      for (int r = 0; r < 4; r++)
        S[(lq * 4 + r) * SP + mt * 16 + lr] = __float2half(cc[r]);
    }
  }
  __syncthreads();

  // ---- P2: single aw sweep; double-buffered 1-group-ahead prefetch ----
  {
    int m0 = l * 4, m1 = 256 + l * 4;
    bool act = (l < 36);       // chunk1 covers m in [256,400) with 36 lanes
    int m1c = act ? m1 : m0;   // clamped: all lanes load a valid address
    const float* awb = aw + (((size_t)(b * 4)) * 400 + n0) * 400;
    float* scb = scores + (((size_t)(b * 8 + hh)) * 400 + n0) * 400;

    float4 A0[4], A1[4], B0[4], B1[4];
    {
      const float* awn = awb + (size_t)w * 400;  // group 0 row
#pragma unroll
      for (int i = 0; i < 4; i++) {
        A0[i] = *(const float4*)(awn + (size_t)i * 160000 + m0);
        A1[i] = *(const float4*)(awn + (size_t)i * 160000 + m1c);
      }
    }

    auto grp = [&](int n, float4 (&c0)[4], float4 (&c1)[4],
                   float4 (&p0)[4], float4 (&p1)[4], bool pf) {
      if (pf) {
        const float* awn = awb + (size_t)(n + 4) * 400;
#pragma unroll
        for (int i = 0; i < 4; i++) {
          p0[i] = *(const float4*)(awn + (size_t)i * 160000 + m0);
          p1[i] = *(const float4*)(awn + (size_t)i * 160000 + m1c);
        }
      }
      _Float16* srow = (_Float16*)S + (size_t)n * SP;
      float* scout = scb + (size_t)n * 400;

      f16x4 s0 = *(const f16x4*)(srow + m0);
      float q0[4], q1[4];
#pragma unroll
      for (int j = 0; j < 4; j++) q0[j] = (float)s0[j];
      if (act) {
        f16x4 s1 = *(const f16x4*)(srow + m1);
#pragma unroll
        for (int j = 0; j < 4; j++) q1[j] = (float)s1[j];
      } else {
#pragma unroll
        for (int j = 0; j < 4; j++) q1[j] = 0.f;
      }

      f16x4 e0[4], e1[4];
      float z[4];
#pragma unroll
      for (int i = 0; i < 4; i++) {
        float zz0 = 0.f, zz1 = 0.f;
#pragma unroll
        for (int j = 0; j < 4; j++) {
          float tt = q0[j] * ((const float*)&c0[i])[j];
          float ef = EXP2(fabsf(tt));
          zz0 += ef;
          e0[i][j] = (_Float16)copysignf(ef, tt);
        }
#pragma unroll
        for (int j = 0; j < 4; j++) {
          float tt = q1[j] * ((const float*)&c1[i])[j];
          float ef = EXP2(fabsf(tt));
          zz1 += ef;
          e1[i][j] = (_Float16)copysignf(ef, tt);
        }
        z[i] = zz0 + (act ? zz1 : 0.f);  // cndmask, no divergence
      }

#pragma unroll
      for (int o = 1; o <= 32; o <<= 1) {
#pragma unroll
        for (int i = 0; i < 4; i++) z[i] += __shfl_xor(z[i], o);
      }

      f16x4 o0, o1;
#pragma unroll
      for (int j = 0; j < 4; j++) { o0[j] = (_Float16)0.f; o1[j] = (_Float16)0.f; }
#pragma unroll
      for (int i = 0; i < 4; i++) {
        _Float16 zh = (_Float16)(0.25f / (z[i] + 1e-10f));  // folds the /NW
        f16x4 zv = {zh, zh, zh, zh};
        o0 += e0[i] * zv;
        o1 += e1[i] * zv;
      }

      float4 so;
#pragma unroll
      for (int j = 0; j < 4; j++) ((float*)&so)[j] = (float)o0[j];
      *(float4*)(scout + m0) = so;
      *(f16x4*)(srow + m0) = o0;
      if (act) {
        float4 s1o;
#pragma unroll
        for (int j = 0; j < 4; j++) ((float*)&s1o)[j] = (float)o1[j];
        *(float4*)(scout + m1) = s1o;
        *(f16x4*)(srow + m1) = o1;
      } else if (l < 40) {
        f16x4 hz;
#pragma unroll
        for (int j = 0; j < 4; j++) hz[j] = (_Float16)0.f;
        *(f16x4*)(srow + m1) = hz;  // zero-pad cols 400..415 for PV chunks
      }
    };

    grp(w,      A0, A1, B0, B1, true);
    grp(4 + w,  B0, B1, A0, A1, true);
    grp(8 + w,  A0, A1, B0, B1, true);
    grp(12 + w, B0, B1, A0, A1, false);
  }
  __syncthreads();

  // ---- P3b: O = S @ V (13 chunks of 32 m, split across 4 waves) ----
  const _Float16* vbase = vt + (((size_t)b) * 256 + hh * 32) * 400;
  f32x4 a0 = {0.f, 0.f, 0.f, 0.f}, a1 = {0.f, 0.f, 0.f, 0.f};
  const _Float16* Sh = (const _Float16*)S;
  for (int c2 = w; c2 < 13; c2 += 4) {
    f16x8 sf = *(const f16x8*)(Sh + lr * SP + c2 * 32 + lq * 8);
    f16x8 v0 = *(const f16x8*)(vbase + (size_t)lr * 400 + c2 * 32 + lq * 8);
    f16x8 v1 = *(const f16x8*)(vbase + (size_t)(16 + lr) * 400 + c2 * 32 + lq * 8);
    a0 = __builtin_amdgcn_mfma_f32_16x16x32_f16(sf, v0, a0, 0, 0, 0);
    a1 = __builtin_amdgcn_mfma_f32_16x16x32_f16(sf, v1, a1, 0, 0, 0);
  }
  __syncthreads();  // all S reads done before overwriting as float scratch
  float* Of = (float*)smem;  // [4w][16n][32d] = 8 KB
#pragma unroll
  for (int r = 0; r < 4; r++) {
    Of[(w * 16 + lq * 4 + r) * 32 + lr] = a0[r];
    Of[(w * 16 + lq * 4 + r) * 32 + 16 + lr] = a1[r];
  }
  __syncthreads();
  for (int o = t; o < 512; o += 256) {
    int n = o >> 5, d = o & 31;
    float s = Of[n * 32 + d] + Of[512 + n * 32 + d] +
              Of[1024 + n * 32 + d] + Of[1536 + n * 32 + d];
    attnb[((size_t)(b * 400 + n0 + n)) * 256 + hh * 32 + d] = f2b(s);
  }
}

// ---------------------------------------------------------------------------
extern "C" void kernel_launch(void* const* d_in, const int* in_sizes, int n_in,
                              void* d_out, int out_size, void* d_ws,
                              size_t ws_size, hipStream_t stream) {
  const float* x   = (const float*)d_in[0];
  const float* aw  = (const float*)d_in[1];
  const float* Wq  = (const float*)d_in[2];
  const float* bq  = (const float*)d_in[3];
  const float* Wk  = (const float*)d_in[4];
  const float* bk  = (const float*)d_in[5];
  const float* Wv  = (const float*)d_in[6];
  const float* bv  = (const float*)d_in[7];
  const float* Wo  = (const float*)d_in[8];
  const float* bo  = (const float*)d_in[9];
  const float* g1  = (const float*)d_in[10];
  const float* be1 = (const float*)d_in[11];
  const float* W1  = (const float*)d_in[12];
  const float* b1  = (const float*)d_in[13];
  const float* W2  = (const float*)d_in[14];
  const float* b2  = (const float*)d_in[15];
  const float* g2  = (const float*)d_in[16];
  const float* be2 = (const float*)d_in[17];

  if (ws_size < 34340864) return;  // scratch layout requirement

  char* ws = (char*)d_ws;
  ushort*   xb    = (ushort*)(ws + 0);          // 3,276,800
  ushort*   wqb   = (ushort*)(ws + 3276800);    //   131,072
  ushort*   wkb   = (ushort*)(ws + 3407872);
  ushort*   wvb   = (ushort*)(ws + 3538944);
  ushort*   wob   = (ushort*)(ws + 3670016);
  ushort*   w1b   = (ushort*)(ws + 3801088);    //   524,288
  ushort*   w2b   = (ushort*)(ws + 4325376);    //   524,288
  _Float16* qhb   = (_Float16*)(ws + 4849664);  // 3,276,800  [b][h][m][32]*scl
  _Float16* khb   = (_Float16*)(ws + 8126464);  //            [b][h][m][32]
  _Float16* vtb   = (_Float16*)(ws + 11403264); //            [b][d][m]
  ushort*   attnb = (ushort*)(ws + 14680064);
  float*    ao    = (float*)(ws + 17956864);    // 6,553,600 (unused now)
  float*    hbuf  = (float*)(ws + 24510464);    // 6,553,600
  ushort*   hb    = (ushort*)(ws + 31064064);   // 3,276,800 -> total 34,340,864
  ushort*   ffn1b = (ushort*)qhb;  // reuse q/k/v region, dead by then
  (void)ao;

  float* yout   = (float*)d_out;
  float* scores = yout + 1638400;

  convert_kernel<<<2368, 256, 0, stream>>>(x, Wq, Wk, Wv, Wo, W1, W2,
                                           xb, wqb, wkb, wvb, wob, w1b, w2b);
  qkv_gemm<<<dim3(4, 100, 3), 256, 0, stream>>>(
      xb, wqb, wkb, wvb, bq, bk, bv, qhb, khb, vtb);
  attn_kernel<<<3200, 256, 0, stream>>>(qhb, khb, vtb, aw, scores, attnb);
  // attn-out GEMM + residual + LN1 fused -> hbuf (f32) + hb (bf16)
  gemm_ln<1><<<200, 256, 0, stream>>>(attnb, wob, bo, x, g1, be1,
                                      hbuf, hb, 256);
  // ffn1: relu(h @ W1^T + b1) -> bf16
  gemm_bt<1, 0, 0, 1><<<dim3(16, 100), 256, 0, stream>>>(
      hb, w1b, b1, nullptr, nullptr, ffn1b, 6400, 1024, 256);
  // ffn2 GEMM + residual + LN2 fused -> yout
  gemm_ln<0><<<200, 256, 0, stream>>>(ffn1b, w2b, b2, hbuf, g2, be2,
                                      yout, nullptr, 1024);
}